// Round 1
// baseline (199.695 us; speedup 1.0000x reference)
//
#include <hip/hip_runtime.h>

// EMA energy normalizer: mag [B,F,T] fp32 -> (mag_norm [B,F,T], mag_mean [B,1,T])
//   frame_means = mean over F; EMA scan over T (m = .99 m + .01 fm, init running_mean);
//   mag_norm = mag / (m + bias + 1e-8)

#define B_  32
#define F_  257
#define T_  3000
#define CHUNKS 8      // F-dimension split for K1 parallelism (750 blocks)
#define FCH 33        // ceil(257/8)
#define MOM 0.99f
#define OMM 0.01f     // 1 - MOM
#define EPS_ 1e-8f

// ---------------------------------------------------------------------------
// K1: partial frame sums. Thread handles (chunk c, batch b, t4) -> float4 sum
// over ~33 f's at stride T. Lanes cover consecutive t4 -> 1KB coalesced
// segments per f step. part layout: [CHUNKS][B][T] floats.
// ---------------------------------------------------------------------------
__global__ __launch_bounds__(256) void k1_partial(const float* __restrict__ mag,
                                                  float* __restrict__ part) {
    int g  = blockIdx.x * 256 + threadIdx.x;   // [0, CHUNKS*B_*750)
    int tt = g % 750;                          // t/4
    int b  = (g / 750) % B_;
    int c  = g / (750 * B_);
    int f0 = c * FCH;
    int f1 = min(f0 + FCH, F_);
    const float4* magv = reinterpret_cast<const float4*>(mag);
    int base = (b * F_ + f0) * 750 + tt;       // float4 index
    float4 s = make_float4(0.f, 0.f, 0.f, 0.f);
    for (int f = f0; f < f1; ++f) {
        float4 v = magv[base];
        s.x += v.x; s.y += v.y; s.z += v.z; s.w += v.w;
        base += 750;
    }
    reinterpret_cast<float4*>(part)[(c * B_ + b) * 750 + tt] = s;
}

// ---------------------------------------------------------------------------
// K2: one block per batch b. Reduce partials -> frame means in LDS, then
// chunked parallel scan of the affine recurrence m' = MOM*m + OMM*x.
// Each chunk is an affine map (A, Bv): m_out = A*m_in + Bv. Hillis-Steele
// composes 256 chunk maps; replay produces exact sequential semantics.
// Writes mag_mean (into d_out tail) and recip table for K3.
// ---------------------------------------------------------------------------
__global__ __launch_bounds__(256) void k2_scan(const float* __restrict__ part,
                                               const float* __restrict__ bias,
                                               const float* __restrict__ rmean,
                                               float* __restrict__ mag_mean,
                                               float* __restrict__ recip) {
    __shared__ float xs[T_];
    __shared__ float sA[256];
    __shared__ float sB[256];
    const int b = blockIdx.x;
    const int tid = threadIdx.x;

    // frame means for this b
    for (int t = tid; t < T_; t += 256) {
        float s = 0.f;
        #pragma unroll
        for (int c = 0; c < CHUNKS; ++c) s += part[(c * B_ + b) * T_ + t];
        xs[t] = s * (1.0f / F_);
    }
    __syncthreads();

    // local chunk scan: 250 active threads x 12 steps = 3000
    const int CH = 12;
    const int t0 = tid * CH;
    float A = 1.f, Bv = 0.f;
    if (t0 < T_) {
        #pragma unroll
        for (int j = 0; j < CH; ++j) {
            float x = xs[t0 + j];
            Bv = MOM * Bv + OMM * x;
            A *= MOM;
        }
    }
    sA[tid] = A; sB[tid] = Bv;
    __syncthreads();

    // Hillis-Steele inclusive scan over (A,B) pairs; earlier ∘ later:
    // (Ap,Bp) then (Ac,Bc) -> (Ap*Ac, Bp*Ac + Bc)
    for (int off = 1; off < 256; off <<= 1) {
        float cA = sA[tid], cB = sB[tid];
        float pA = 1.f, pB = 0.f;
        if (tid >= off) { pA = sA[tid - off]; pB = sB[tid - off]; }
        __syncthreads();
        if (tid >= off) { sA[tid] = pA * cA; sB[tid] = pB * cA + cB; }
        __syncthreads();
    }

    // exclusive prefix = inclusive of tid-1
    float pA = 1.f, pB = 0.f;
    if (tid > 0) { pA = sA[tid - 1]; pB = sB[tid - 1]; }

    if (t0 < T_) {
        float m = pA * rmean[0] + pB;   // m_{t0-1}
        float bias0 = bias[0];
        #pragma unroll
        for (int j = 0; j < CH; ++j) {
            float x = xs[t0 + j];
            m = MOM * m + OMM * x;
            float mb = m + bias0;
            mag_mean[b * T_ + t0 + j] = mb;
            recip[b * T_ + t0 + j] = 1.0f / (mb + EPS_);
        }
    }
}

// ---------------------------------------------------------------------------
// K3: mag_norm = mag * recip[b][t]. One float4 per thread, fully coalesced.
// mag re-read expected to hit Infinity Cache (just streamed by K1).
// ---------------------------------------------------------------------------
__global__ __launch_bounds__(256) void k3_norm(const float* __restrict__ mag,
                                               const float* __restrict__ recip,
                                               float* __restrict__ out) {
    const int N4 = B_ * F_ * T_ / 4;
    int i4 = blockIdx.x * 256 + threadIdx.x;
    if (i4 >= N4) return;
    float4 v = reinterpret_cast<const float4*>(mag)[i4];
    int b  = i4 / (F_ * T_ / 4);     // i4 / 192750
    int t4 = i4 % (T_ / 4);          // i4 % 750
    float4 r = reinterpret_cast<const float4*>(recip)[b * (T_ / 4) + t4];
    float4 o;
    o.x = v.x * r.x; o.y = v.y * r.y; o.z = v.z * r.z; o.w = v.w * r.w;
    reinterpret_cast<float4*>(out)[i4] = o;
}

extern "C" void kernel_launch(void* const* d_in, const int* in_sizes, int n_in,
                              void* d_out, int out_size, void* d_ws, size_t ws_size,
                              hipStream_t stream) {
    const float* mag   = (const float*)d_in[0];
    const float* bias  = (const float*)d_in[1];
    const float* rmean = (const float*)d_in[2];
    float* out      = (float*)d_out;
    float* mag_mean = out + (size_t)B_ * F_ * T_;   // second tuple output
    float* part  = (float*)d_ws;                    // CHUNKS*B*T floats = 3 MB
    float* recip = part + (size_t)CHUNKS * B_ * T_; // B*T floats = 384 KB

    k1_partial<<<CHUNKS * B_ * 750 / 256, 256, 0, stream>>>(mag, part);
    k2_scan<<<B_, 256, 0, stream>>>(part, bias, rmean, mag_mean, recip);
    const int N4 = B_ * F_ * T_ / 4;
    k3_norm<<<(N4 + 255) / 256, 256, 0, stream>>>(mag, recip, out);
}